// Round 11
// baseline (40.735 us; speedup 1.0000x reference)
//
#include <hip/hip_runtime.h>
#include <math.h>

#define NM    4096          // output modes
#define HALFN 2048
#define MR    8192          // oversampled grid (2x)
#define MRM   (MR - 1)
#define STPB  512           // spread threads per block
#define NB    256           // partial grids
#define W     6             // Gaussian taps (E = 6.66, err ~1.3e-3 rel)
#define FSCALE 65536.0f     // fixed-point scale 2^16
#define INVFS  (1.0f / 65536.0f)
#define PAD(i) ((i) + ((i) >> 5))   // LDS bank-conflict padding

// hw trig/exp: v_sin/v_cos take REVOLUTIONS; v_exp_f32 computes 2^x.
__device__ __forceinline__ float sin2pi(float r) {
    float o; asm volatile("v_sin_f32 %0, %1" : "=v"(o) : "v"(r)); return o;
}
__device__ __forceinline__ float cos2pi(float r) {
    float o; asm volatile("v_cos_f32 %0, %1" : "=v"(o) : "v"(r)); return o;
}
__device__ __forceinline__ float exp2a(float x) {
    float o; asm volatile("v_exp_f32 %0, %1" : "=v"(o) : "v"(x)); return o;
}

// ---------------- 1) spread: points -> privatized LDS int grid -> int partials
// wgt_i = exp(-alpha*(t0+i)^2) = E1 * r^i * C[i]  (2 exps/point, 2 muls/tap).
// ws layout (ints): [0,16384) = final int grid G (re|im planar, atomically
// accumulated by reduce; zeroed here by block 0);
// [16384 + b*16384, ...) = block b's partial grid (int, re|im planar).
__global__ __launch_bounds__(STPB) void nufft_spread(
    const float* __restrict__ pts, const float* __restrict__ vre,
    const float* __restrict__ vim, float* __restrict__ ws,
    int M, int ppb, float nalpha, float4 cA, float2 cB)
{
    __shared__ int gre[MR];
    __shared__ int gim[MR];
    const int tid = threadIdx.x;
    const int b   = blockIdx.x;
    const float C[W] = {cA.x, cA.y, cA.z, cA.w, cB.x, cB.y};

    if (b == 0) {                      // zero final grid G (before reduce runs)
        int4 z = make_int4(0, 0, 0, 0);
        int4* G4 = (int4*)ws;
        for (int i = tid; i < MR / 2; i += STPB) G4[i] = z;
    }
    for (int i = tid; i < MR; i += STPB) { gre[i] = 0; gim[i] = 0; }
    __syncthreads();

    const int j0   = b * ppb;
    const int jend = min(j0 + ppb, M);
    const float inv2pi = 0.15915494309189535f;

    for (int j = j0 + tid; j < jend; j += STPB) {
        float x  = pts[j];
        float cr = vre[j];
        float ci = vim[j];
        float u = x * inv2pi;
        u -= floorf(u);                 // [0,1)
        float p  = u * (float)MR;       // grid position [0, 8192]
        float fl = floorf(p);
        int   i0 = (int)fl - 2;
        float t0 = (fl - p) - 2.0f;     // m - p for m = i0, in (-3, -2]
        float E1 = exp2a(nalpha * t0 * t0);      // exp(-alpha*t0^2)
        float r  = exp2a(2.0f * nalpha * t0);    // exp(-2*alpha*t0)
        float crs = cr * FSCALE * E1;
        float cis = ci * FSCALE * E1;
        float w = 1.0f;
#pragma unroll
        for (int i = 0; i < W; ++i) {
            float wgt = w * C[i];
            int m = (i0 + i) & MRM;
            atomicAdd(&gre[m], (int)(wgt * crs));   // native ds_add_u32
            atomicAdd(&gim[m], (int)(wgt * cis));
            w *= r;
        }
    }
    __syncthreads();

    // raw int writeback, vectorized
    int4* buf = (int4*)((int*)ws + 16384 + (size_t)b * 16384);
    const int4* g4r = (const int4*)gre;
    const int4* g4i = (const int4*)gim;
    for (int i = tid; i < MR / 4; i += STPB) {
        buf[i]          = g4r[i];
        buf[MR / 4 + i] = g4i[i];
    }
}

// ---------------- 2) reduce int partials -> int grid G (atomic combine) -----
// 16384 threads = 4 b-chunks x 4096 int4-columns. int4 loads keep 2 MB in
// flight (vs 512 KB scalar) -> ~4x read BW. Int atomics: order-independent,
// bit-deterministic.
__global__ __launch_bounds__(256) void nufft_reduce_grid(
    float* __restrict__ ws, int nb, int per)
{
    int t = blockIdx.x * 256 + threadIdx.x;          // [0, 16384)
    int col4  = t & 4095;                            // int4 column
    int chunk = t >> 12;                             // 0..3
    int b0 = chunk * per;
    int b1 = min(b0 + per, nb);
    const int4* base = (const int4*)((const int*)ws + 16384);
    int4 s = make_int4(0, 0, 0, 0);
    for (int b = b0; b < b1; ++b) {
        int4 v = base[(size_t)b * 4096 + col4];
        s.x += v.x; s.y += v.y; s.z += v.z; s.w += v.w;
    }
    int* G = (int*)ws;
    atomicAdd(&G[col4 * 4 + 0], s.x);
    atomicAdd(&G[col4 * 4 + 1], s.y);
    atomicAdd(&G[col4 * 4 + 2], s.z);
    atomicAdd(&G[col4 * 4 + 3], s.w);
}

// ---------------- 3) single-block 8192-pt DIF FFT (+i) + deconv + output ----
// radix-2 stage then 6 radix-4 stages, natural input, digit-reversed output;
// deconv resolves the digit reversal at read time. LDS padded (i + i/32).
// Twiddles: w1 via hw trig, w2 = w1^2, w3 = w1*w2 (trans pipe is 1/4 rate).
__global__ __launch_bounds__(1024) void nufft_fft(
    const float* __restrict__ ws, float* __restrict__ out,
    int out_size, float sfac, float taul2e)
{
    __shared__ float re[MR + MR / 32];
    __shared__ float im[MR + MR / 32];
    const int tid = threadIdx.x;
    const int* gi = (const int*)ws;

    for (int q = tid; q < MR; q += 1024) {
        re[PAD(q)] = (float)gi[q]      * INVFS;
        im[PAD(q)] = (float)gi[MR + q] * INVFS;
    }
    __syncthreads();

    // radix-2 DIF: y0 = a+b (k even half), y1 = (a-b)*w^t (k odd half)
    for (int t = tid; t < MR / 2; t += 1024) {
        int ia = PAD(t), ib = PAD(t + MR / 2);
        float ar = re[ia], ai = im[ia];
        float br = re[ib], bi = im[ib];
        re[ia] = ar + br;  im[ia] = ai + bi;
        float dr = ar - br, di = ai - bi;
        float tf = (float)t * (1.0f / (float)MR);
        float wr = cos2pi(tf), wi = sin2pi(tf);      // e^{+2pi i t/8192}
        re[ib] = fmaf(dr, wr, -(di * wi));
        im[ib] = fmaf(dr, wi,   di * wr);
    }
    __syncthreads();

    // radix-4 DIF stages: span h = 1024,256,64,16,4,1  (L = 4h)
    for (int lh = 10; lh >= 0; lh -= 2) {
        int h = 1 << lh;
        float invL = 1.0f / (float)(h << 2);
        for (int idx = tid; idx < MR / 4; idx += 1024) {
            int t    = idx & (h - 1);
            int base = ((idx >> lh) << (lh + 2)) + t;
            int ia = PAD(base), ib = PAD(base + h), ic = PAD(base + 2 * h), id = PAD(base + 3 * h);
            float ar = re[ia], ai = im[ia];
            float br = re[ib], bi = im[ib];
            float cr = re[ic], ci = im[ic];
            float dr = re[id], di = im[id];
            float er = ar + cr, ei = ai + ci;        // a + c
            float fr = ar - cr, fi = ai - ci;        // a - c
            float gr = br + dr, gi2 = bi + di;       // b + d
            float hr = br - dr, hi = bi - di;        // b - d
            // y0 = e+g ; y1 = (f + i*h)*w ; y2 = (e-g)*w^2 ; y3 = (f - i*h)*w^3
            float y1r = fr - hi, y1i = fi + hr;
            float y2r = er - gr, y2i = ei - gi2;
            float y3r = fr + hi, y3i = fi - hr;
            float tf  = (float)t * invL;             // < 0.25
            float w1r = cos2pi(tf), w1i = sin2pi(tf);
            float w2r = fmaf(w1r, w1r, -(w1i * w1i));    // w1^2
            float w2i = 2.0f * w1r * w1i;
            float w3r = fmaf(w2r, w1r, -(w2i * w1i));    // w1^3
            float w3i = fmaf(w2r, w1i,   w2i * w1r);
            re[ia] = er + gr;  im[ia] = ei + gi2;
            re[ib] = fmaf(y1r, w1r, -(y1i * w1i));
            im[ib] = fmaf(y1r, w1i,   y1i * w1r);
            re[ic] = fmaf(y2r, w2r, -(y2i * w2i));
            im[ic] = fmaf(y2r, w2i,   y2i * w2r);
            re[id] = fmaf(y3r, w3r, -(y3i * w3i));
            im[id] = fmaf(y3r, w3i,   y3i * w3r);
        }
        __syncthreads();
    }

    // deconvolve + write planar modes; storage index = digit-reversal of k8
    for (int idx = tid; idx < NM; idx += 1024) {
        int k   = (idx < HALFN) ? idx : idx - NM;
        int k8  = (idx < HALFN) ? idx : idx + NM;    // k mod 8192
        int s0 = k8 & 1, v = k8 >> 1;
        int p = (s0 << 12) | ((v & 3) << 10) | (((v >> 2) & 3) << 8)
              | (((v >> 4) & 3) << 6) | (((v >> 6) & 3) << 4)
              | (((v >> 8) & 3) << 2) | ((v >> 10) & 3);
        float kk = (float)k;
        float corr = sfac * exp2a(kk * kk * taul2e); // sfac * e^{k^2 tau}
        float fre = re[PAD(p)] * corr;
        float fim = im[PAD(p)] * corr;
        if (out_size >= 2 * NM) {
            out[idx]      = fre;
            out[NM + idx] = fim;
        } else {
            out[idx] = fre;
        }
    }
}

extern "C" void kernel_launch(void* const* d_in, const int* in_sizes, int n_in,
                              void* d_out, int out_size, void* d_ws, size_t ws_size,
                              hipStream_t stream)
{
    const float* pts = (const float*)d_in[0];
    const float* vre = (const float*)d_in[1];
    const float* vim = (const float*)d_in[2];
    float* out = (float*)d_out;
    float* ws  = (float*)d_ws;
    const int M = in_sizes[0];

    // Gaussian kernel, w=6, balanced: alpha = gam*sqrt(dif)/6, E = 9*alpha = 6.66
    const double PI  = 3.14159265358979323846;
    const double gam = 2.0 * PI / (double)MR;
    const double dif = (double)(MR - HALFN) * (MR - HALFN) - (double)HALFN * HALFN;
    const double alpha = gam * sqrt(dif) / 6.0;
    const double tau = gam * gam / (4.0 * alpha);
    const double L2E = 1.4426950408889634;
    const float nalpha = (float)(-alpha * L2E);                // exp2 scale
    const float sfac   = (float)sqrt(alpha / PI);
    const float taul2e = (float)(tau * L2E);
    float4 cA = make_float4(1.0f, (float)exp(-alpha), (float)exp(-alpha * 4.0),
                            (float)exp(-alpha * 9.0));
    float2 cB = make_float2((float)exp(-alpha * 16.0), (float)exp(-alpha * 25.0));

    int nb = NB;
    while (nb > 1 && (size_t)(nb + 1) * 65536 > ws_size) nb >>= 1;
    int ppb = (M + nb - 1) / nb;
    int per = (nb + 3) / 4;

    hipLaunchKernelGGL(nufft_spread, dim3(nb), dim3(STPB), 0, stream,
                       pts, vre, vim, ws, M, ppb, nalpha, cA, cB);
    hipLaunchKernelGGL(nufft_reduce_grid, dim3(64), dim3(256), 0, stream, ws, nb, per);
    hipLaunchKernelGGL(nufft_fft, dim3(1), dim3(1024), 0, stream,
                       ws, out, out_size, sfac, taul2e);
}

// Round 12
// 39.550 us; speedup vs baseline: 1.0300x; 1.0300x over previous
//
#include <hip/hip_runtime.h>
#include <math.h>

#define NM    4096          // output modes
#define HALFN 2048
#define MR    8192          // oversampled grid (2x)
#define MRM   (MR - 1)
#define STPB  512           // spread threads per block
#define NB    256           // spread blocks
#define W     6             // Gaussian taps (E = 6.66, err ~1.3e-3 rel)
#define FSCALE 65536.0f     // fixed-point scale 2^16
#define INVFS  (1.0f / 65536.0f)
#define PAD(i) ((i) + ((i) >> 5))   // LDS bank-conflict padding

// hw trig/exp: v_sin/v_cos take REVOLUTIONS; v_exp_f32 computes 2^x.
__device__ __forceinline__ float sin2pi(float r) {
    float o; asm volatile("v_sin_f32 %0, %1" : "=v"(o) : "v"(r)); return o;
}
__device__ __forceinline__ float cos2pi(float r) {
    float o; asm volatile("v_cos_f32 %0, %1" : "=v"(o) : "v"(r)); return o;
}
__device__ __forceinline__ float exp2a(float x) {
    float o; asm volatile("v_exp_f32 %0, %1" : "=v"(o) : "v"(x)); return o;
}

// ---------------- 1) spread: points -> LDS int grid -> global atomic combine
// wgt_i = exp(-alpha*(t0+i)^2) = E1 * r^i * C[i]  (2 exps/point, 2 muls/tap).
// ws layout (ints): [0,8192) = G.re, [8192,16384) = G.im. G zeroed by memset.
// Int atomics are associative -> deterministic in any completion order.
__global__ __launch_bounds__(STPB) void nufft_spread(
    const float* __restrict__ pts, const float* __restrict__ vre,
    const float* __restrict__ vim, float* __restrict__ ws,
    int M, int ppb, float nalpha, float4 cA, float2 cB)
{
    __shared__ int gre[MR];
    __shared__ int gim[MR];
    const int tid = threadIdx.x;
    const int b   = blockIdx.x;
    const float C[W] = {cA.x, cA.y, cA.z, cA.w, cB.x, cB.y};

    for (int i = tid; i < MR; i += STPB) { gre[i] = 0; gim[i] = 0; }
    __syncthreads();

    const int j0   = b * ppb;
    const int jend = min(j0 + ppb, M);
    const float inv2pi = 0.15915494309189535f;

    for (int j = j0 + tid; j < jend; j += STPB) {
        float x  = pts[j];
        float cr = vre[j];
        float ci = vim[j];
        float u = x * inv2pi;
        u -= floorf(u);                 // [0,1)
        float p  = u * (float)MR;       // grid position [0, 8192]
        float fl = floorf(p);
        int   i0 = (int)fl - 2;
        float t0 = (fl - p) - 2.0f;     // m - p for m = i0, in (-3, -2]
        float E1 = exp2a(nalpha * t0 * t0);      // exp(-alpha*t0^2)
        float r  = exp2a(2.0f * nalpha * t0);    // exp(-2*alpha*t0)
        float crs = cr * FSCALE * E1;
        float cis = ci * FSCALE * E1;
        float w = 1.0f;
#pragma unroll
        for (int i = 0; i < W; ++i) {
            float wgt = w * C[i];
            int m = (i0 + i) & MRM;
            atomicAdd(&gre[m], (int)(wgt * crs));   // native ds_add_u32
            atomicAdd(&gim[m], (int)(wgt * cis));
            w *= r;
        }
    }
    __syncthreads();

    // combine into global grid: coalesced fire-and-forget int atomics
    int* G = (int*)ws;
    for (int i = tid; i < MR; i += STPB) {
        int vr = gre[i];
        int vi = gim[i];
        if (vr) atomicAdd(&G[i], vr);
        if (vi) atomicAdd(&G[MR + i], vi);
    }
}

// ---------------- 2) single-block 8192-pt DIF FFT (+i) + deconv + output ----
// radix-2 stage then 6 radix-4 stages, natural input, digit-reversed output;
// deconv resolves the digit reversal at read time. LDS padded (i + i/32).
// Twiddles: w1 via hw trig, w2 = w1^2, w3 = w1*w2 (trans pipe is 1/4 rate).
__global__ __launch_bounds__(1024) void nufft_fft(
    const float* __restrict__ ws, float* __restrict__ out,
    int out_size, float sfac, float taul2e)
{
    __shared__ float re[MR + MR / 32];
    __shared__ float im[MR + MR / 32];
    const int tid = threadIdx.x;
    const int* gi = (const int*)ws;

    for (int q = tid; q < MR; q += 1024) {
        re[PAD(q)] = (float)gi[q]      * INVFS;
        im[PAD(q)] = (float)gi[MR + q] * INVFS;
    }
    __syncthreads();

    // radix-2 DIF: y0 = a+b (k even half), y1 = (a-b)*w^t (k odd half)
    for (int t = tid; t < MR / 2; t += 1024) {
        int ia = PAD(t), ib = PAD(t + MR / 2);
        float ar = re[ia], ai = im[ia];
        float br = re[ib], bi = im[ib];
        re[ia] = ar + br;  im[ia] = ai + bi;
        float dr = ar - br, di = ai - bi;
        float tf = (float)t * (1.0f / (float)MR);
        float wr = cos2pi(tf), wi = sin2pi(tf);      // e^{+2pi i t/8192}
        re[ib] = fmaf(dr, wr, -(di * wi));
        im[ib] = fmaf(dr, wi,   di * wr);
    }
    __syncthreads();

    // radix-4 DIF stages: span h = 1024,256,64,16,4,1  (L = 4h)
    for (int lh = 10; lh >= 0; lh -= 2) {
        int h = 1 << lh;
        float invL = 1.0f / (float)(h << 2);
        for (int idx = tid; idx < MR / 4; idx += 1024) {
            int t    = idx & (h - 1);
            int base = ((idx >> lh) << (lh + 2)) + t;
            int ia = PAD(base), ib = PAD(base + h), ic = PAD(base + 2 * h), id = PAD(base + 3 * h);
            float ar = re[ia], ai = im[ia];
            float br = re[ib], bi = im[ib];
            float cr = re[ic], ci = im[ic];
            float dr = re[id], di = im[id];
            float er = ar + cr, ei = ai + ci;        // a + c
            float fr = ar - cr, fi = ai - ci;        // a - c
            float gr = br + dr, gi2 = bi + di;       // b + d
            float hr = br - dr, hi = bi - di;        // b - d
            // y0 = e+g ; y1 = (f + i*h)*w ; y2 = (e-g)*w^2 ; y3 = (f - i*h)*w^3
            float y1r = fr - hi, y1i = fi + hr;
            float y2r = er - gr, y2i = ei - gi2;
            float y3r = fr + hi, y3i = fi - hr;
            float tf  = (float)t * invL;             // < 0.25
            float w1r = cos2pi(tf), w1i = sin2pi(tf);
            float w2r = fmaf(w1r, w1r, -(w1i * w1i));    // w1^2
            float w2i = 2.0f * w1r * w1i;
            float w3r = fmaf(w2r, w1r, -(w2i * w1i));    // w1^3
            float w3i = fmaf(w2r, w1i,   w2i * w1r);
            re[ia] = er + gr;  im[ia] = ei + gi2;
            re[ib] = fmaf(y1r, w1r, -(y1i * w1i));
            im[ib] = fmaf(y1r, w1i,   y1i * w1r);
            re[ic] = fmaf(y2r, w2r, -(y2i * w2i));
            im[ic] = fmaf(y2r, w2i,   y2i * w2r);
            re[id] = fmaf(y3r, w3r, -(y3i * w3i));
            im[id] = fmaf(y3r, w3i,   y3i * w3r);
        }
        __syncthreads();
    }

    // deconvolve + write planar modes; storage index = digit-reversal of k8
    for (int idx = tid; idx < NM; idx += 1024) {
        int k   = (idx < HALFN) ? idx : idx - NM;
        int k8  = (idx < HALFN) ? idx : idx + NM;    // k mod 8192
        int s0 = k8 & 1, v = k8 >> 1;
        int p = (s0 << 12) | ((v & 3) << 10) | (((v >> 2) & 3) << 8)
              | (((v >> 4) & 3) << 6) | (((v >> 6) & 3) << 4)
              | (((v >> 8) & 3) << 2) | ((v >> 10) & 3);
        float kk = (float)k;
        float corr = sfac * exp2a(kk * kk * taul2e); // sfac * e^{k^2 tau}
        float fre = re[PAD(p)] * corr;
        float fim = im[PAD(p)] * corr;
        if (out_size >= 2 * NM) {
            out[idx]      = fre;
            out[NM + idx] = fim;
        } else {
            out[idx] = fre;
        }
    }
}

extern "C" void kernel_launch(void* const* d_in, const int* in_sizes, int n_in,
                              void* d_out, int out_size, void* d_ws, size_t ws_size,
                              hipStream_t stream)
{
    const float* pts = (const float*)d_in[0];
    const float* vre = (const float*)d_in[1];
    const float* vim = (const float*)d_in[2];
    float* out = (float*)d_out;
    float* ws  = (float*)d_ws;
    const int M = in_sizes[0];

    // Gaussian kernel, w=6, balanced: alpha = gam*sqrt(dif)/6, E = 9*alpha = 6.66
    const double PI  = 3.14159265358979323846;
    const double gam = 2.0 * PI / (double)MR;
    const double dif = (double)(MR - HALFN) * (MR - HALFN) - (double)HALFN * HALFN;
    const double alpha = gam * sqrt(dif) / 6.0;
    const double tau = gam * gam / (4.0 * alpha);
    const double L2E = 1.4426950408889634;
    const float nalpha = (float)(-alpha * L2E);                // exp2 scale
    const float sfac   = (float)sqrt(alpha / PI);
    const float taul2e = (float)(tau * L2E);
    float4 cA = make_float4(1.0f, (float)exp(-alpha), (float)exp(-alpha * 4.0),
                            (float)exp(-alpha * 9.0));
    float2 cB = make_float2((float)exp(-alpha * 16.0), (float)exp(-alpha * 25.0));

    int nb = NB;
    int ppb = (M + nb - 1) / nb;

    hipMemsetAsync(ws, 0, 2 * MR * sizeof(int), stream);   // zero int grid G
    hipLaunchKernelGGL(nufft_spread, dim3(nb), dim3(STPB), 0, stream,
                       pts, vre, vim, ws, M, ppb, nalpha, cA, cB);
    hipLaunchKernelGGL(nufft_fft, dim3(1), dim3(1024), 0, stream,
                       ws, out, out_size, sfac, taul2e);
}